// Round 1
// baseline (65.165 us; speedup 1.0000x reference)
//
#include <hip/hip_runtime.h>
#include <hip/hip_bf16.h>
#include <stdint.h>

#define NB 4096
#define NS 64
#define ND 512
#define K1 1088   // 1026 padded to multiple of 64
#define K2 1024
#define EPSV 1e-8f

typedef float f32x4 __attribute__((ext_vector_type(4)));
typedef short bf16x8 __attribute__((ext_vector_type(8)));

__device__ __forceinline__ short f2bf(float f) {
    union { float f; unsigned u; } v; v.f = f;
    unsigned r = v.u + 0x7fffu + ((v.u >> 16) & 1u);
    return (short)(r >> 16);
}
__device__ __forceinline__ float sigm(float x) { return 1.0f / (1.0f + expf(-x)); }

// ---------------- prep1: cosine sims + X2=[Bv|A] bf16 + X1 tail ----------------
__global__ __launch_bounds__(256) void prep1(
    const int* __restrict__ ip, const float* __restrict__ src,
    const float* __restrict__ Aa, const float* __restrict__ sv,
    short* __restrict__ X1, short* __restrict__ X2)
{
    const int i = *ip;
    const int w = threadIdx.x >> 6, lane = threadIdx.x & 63;
    const int b = blockIdx.x * 4 + w;
    const float* Arow = Aa + (size_t)b * ND;
    const float* Brow = src + ((size_t)b * NS + i) * ND;
    const float* Srow = sv + (size_t)b * ND;
    short* x2row = X2 + (size_t)b * K2;

    float dab = 0.f, daa = 0.f, dbb = 0.f, das = 0.f, dss = 0.f;
    #pragma unroll
    for (int c = 0; c < 2; ++c) {
        const int d0 = c * 256 + lane * 4;
        f32x4 a  = *(const f32x4*)(Arow + d0);
        f32x4 bv = *(const f32x4*)(Brow + d0);
        f32x4 s  = *(const f32x4*)(Srow + d0);
        #pragma unroll
        for (int j = 0; j < 4; ++j) {
            dab += a[j] * bv[j];
            daa += a[j] * a[j];
            dbb += bv[j] * bv[j];
            das += a[j] * s[j];
            dss += s[j] * s[j];
        }
        short4 qb, qa;
        qb.x = f2bf(bv[0]); qb.y = f2bf(bv[1]); qb.z = f2bf(bv[2]); qb.w = f2bf(bv[3]);
        qa.x = f2bf(a[0]);  qa.y = f2bf(a[1]);  qa.z = f2bf(a[2]);  qa.w = f2bf(a[3]);
        *(short4*)(x2row + d0) = qb;
        *(short4*)(x2row + 512 + d0) = qa;
    }
    #pragma unroll
    for (int off = 32; off; off >>= 1) {
        dab += __shfl_xor(dab, off);
        daa += __shfl_xor(daa, off);
        dbb += __shfl_xor(dbb, off);
        das += __shfl_xor(das, off);
        dss += __shfl_xor(dss, off);
    }
    const float na = fmaxf(sqrtf(daa), EPSV);
    const float nb = fmaxf(sqrtf(dbb), EPSV);
    const float ns = fmaxf(sqrtf(dss), EPSV);
    const float pcv = dab / (na * nb);
    const float ptv = das / (na * ns);
    short* x1row = X1 + (size_t)b * K1;
    if (lane == 0) { x1row[1024] = f2bf(pcv); x1row[1025] = f2bf(ptv); }
    if (lane < 62) x1row[1026 + lane] = 0;   // zero pad cols 1026..1087
}

// ---------------- prep2: enc_memory[i] -> X1 bf16 (cols 0..1023) ----------------
__global__ __launch_bounds__(256) void prep2(
    const int* __restrict__ ip, const float* __restrict__ enc, short* __restrict__ X1)
{
    const int i = *ip;
    const int idx = blockIdx.x * 256 + threadIdx.x;   // 4096*256 threads, 4 elems each
    const int b = idx >> 8;
    const int k4 = (idx & 255) * 4;
    f32x4 v = *(const f32x4*)(enc + ((size_t)i * NB + b) * 1024 + k4);
    short4 q;
    q.x = f2bf(v[0]); q.y = f2bf(v[1]); q.z = f2bf(v[2]); q.w = f2bf(v[3]);
    *(short4*)(X1 + (size_t)b * K1 + k4) = q;
}

// ---------------- build_w: pack bf16 weight blocks ----------------
__global__ __launch_bounds__(256) void build_w(
    const float* __restrict__ Wfg, const float* __restrict__ Wig,
    const float* __restrict__ Wogb, const float* __restrict__ WogA,
    const float* __restrict__ Wctb,
    short* __restrict__ W1, short* __restrict__ W2)
{
    const size_t idx = (size_t)blockIdx.x * 256 + threadIdx.x;
    const size_t n1 = (size_t)1024 * K1;
    if (idx < n1) {
        const int n = (int)(idx / K1), k = (int)(idx % K1);
        float v = 0.f;
        if (k < 1026) v = (n < 512) ? Wfg[(size_t)n * 1026 + k] : Wig[(size_t)(n - 512) * 1026 + k];
        W1[idx] = f2bf(v);
    } else {
        const size_t j = idx - n1;
        if (j < (size_t)1024 * 1024) {
            const int n = (int)(j >> 10), k = (int)(j & 1023);
            float v;
            if (n < 512) v = (k < 512) ? Wogb[(size_t)n * 512 + k] : WogA[(size_t)n * 512 + (k - 512)];
            else         v = (k < 512) ? Wctb[(size_t)(n - 512) * 512 + k] : 0.f;
            W2[j] = f2bf(v);
        }
    }
}

// ---------------- gemm: C(4096x1024) = X(4096xK) @ W(1024xK)^T, bf16 MFMA ----------------
__global__ __launch_bounds__(256) void gemm_bt(
    const short* __restrict__ X1v, const short* __restrict__ W1v, float* __restrict__ G1v,
    const short* __restrict__ X2v, const short* __restrict__ W2v, float* __restrict__ G2v)
{
    const bool second = (blockIdx.z != 0);
    const short* Xp = second ? X2v : X1v;
    const short* Wp = second ? W2v : W1v;
    float* Gp = second ? G2v : G1v;
    const int K = second ? K2 : K1;

    __shared__ __align__(16) short As[128 * 64];
    __shared__ __align__(16) short Bs[128 * 64];

    const int tid = threadIdx.x;
    const int w = tid >> 6, lane = tid & 63;
    const int wm = w >> 1, wn = w & 1;
    const int lr = lane & 15, lg = lane >> 4;

    const size_t ldb = (size_t)K * 2;   // row stride in bytes
    const char* Xb = (const char*)Xp + (size_t)blockIdx.x * 128 * ldb;
    const char* Wb = (const char*)Wp + (size_t)blockIdx.y * 128 * ldb;

    f32x4 acc[4][4];
    #pragma unroll
    for (int mi = 0; mi < 4; ++mi)
        #pragma unroll
        for (int ni = 0; ni < 4; ++ni)
            acc[mi][ni] = f32x4{0.f, 0.f, 0.f, 0.f};

    const int nkt = K >> 6;
    for (int kt = 0; kt < nkt; ++kt) {
        __syncthreads();   // previous compute done before overwriting LDS
        // stage A tile: 128 rows x 64 bf16 = 16KB, linear; wave-uniform LDS base + per-lane global
        #pragma unroll
        for (int s = 0; s < 4; ++s) {
            const int seg = (s * 4 + w) * 1024;
            const int linear = seg + lane * 16;
            const int row = linear >> 7, kb = linear & 127;
            __builtin_amdgcn_global_load_lds(
                (const __attribute__((address_space(1))) void*)(Xb + (size_t)row * ldb + (size_t)kt * 128 + kb),
                (__attribute__((address_space(3))) void*)((char*)As + seg),
                16, 0, 0);
        }
        #pragma unroll
        for (int s = 0; s < 4; ++s) {
            const int seg = (s * 4 + w) * 1024;
            const int linear = seg + lane * 16;
            const int row = linear >> 7, kb = linear & 127;
            __builtin_amdgcn_global_load_lds(
                (const __attribute__((address_space(1))) void*)(Wb + (size_t)row * ldb + (size_t)kt * 128 + kb),
                (__attribute__((address_space(3))) void*)((char*)Bs + seg),
                16, 0, 0);
        }
        __syncthreads();   // compiler drains vmcnt(0) before s_barrier
        #pragma unroll
        for (int ks = 0; ks < 2; ++ks) {
            bf16x8 af[4], bfr[4];
            #pragma unroll
            for (int mi = 0; mi < 4; ++mi)
                af[mi] = *(const bf16x8*)((const char*)As + (wm * 64 + mi * 16 + lr) * 128 + ks * 64 + lg * 16);
            #pragma unroll
            for (int ni = 0; ni < 4; ++ni)
                bfr[ni] = *(const bf16x8*)((const char*)Bs + (wn * 64 + ni * 16 + lr) * 128 + ks * 64 + lg * 16);
            #pragma unroll
            for (int mi = 0; mi < 4; ++mi)
                #pragma unroll
                for (int ni = 0; ni < 4; ++ni)
                    acc[mi][ni] = __builtin_amdgcn_mfma_f32_16x16x32_bf16(af[mi], bfr[ni], acc[mi][ni], 0, 0, 0);
        }
    }

    // epilogue: C/D layout col=lane&15, row=(lane>>4)*4+reg (m89/m91)
    float* Grow = Gp + ((size_t)blockIdx.x * 128 + wm * 64) * 1024 + blockIdx.y * 128 + wn * 64;
    #pragma unroll
    for (int mi = 0; mi < 4; ++mi)
        #pragma unroll
        for (int ni = 0; ni < 4; ++ni)
            #pragma unroll
            for (int r = 0; r < 4; ++r)
                Grow[(size_t)(mi * 16 + lg * 4 + r) * 1024 + ni * 16 + lr] = acc[mi][ni][r];
}

// ---------------- finish: gates + score + out ----------------
__global__ __launch_bounds__(256) void finish_k(
    const int* __restrict__ ip, const float* __restrict__ src, const float* __restrict__ Aa,
    const float* __restrict__ G1v, const float* __restrict__ G2v,
    const float* __restrict__ bfg, const float* __restrict__ big,
    const float* __restrict__ bogb, const float* __restrict__ bogA, const float* __restrict__ bctb,
    const float* __restrict__ fw, const float* __restrict__ fb,
    float* __restrict__ out)
{
    const int i = *ip;
    const int w = threadIdx.x >> 6, lane = threadIdx.x & 63;
    const int b = blockIdx.x * 4 + w;
    const float* Arow = Aa + (size_t)b * ND;
    const float* Brow = src + ((size_t)b * NS + i) * ND;
    const float* g1 = G1v + (size_t)b * 1024;
    const float* g2 = G2v + (size_t)b * 1024;

    float hsum = 0.f;
    float av[8], bvv[8];
    #pragma unroll
    for (int c = 0; c < 2; ++c) {
        const int d0 = c * 256 + lane * 4;
        f32x4 vfg = *(const f32x4*)(g1 + d0);
        f32x4 vig = *(const f32x4*)(g1 + 512 + d0);
        f32x4 vog = *(const f32x4*)(g2 + d0);
        f32x4 vct = *(const f32x4*)(g2 + 512 + d0);
        f32x4 va  = *(const f32x4*)(Arow + d0);
        f32x4 vb  = *(const f32x4*)(Brow + d0);
        f32x4 c1  = *(const f32x4*)(bfg + d0);
        f32x4 c2  = *(const f32x4*)(big + d0);
        f32x4 c3  = *(const f32x4*)(bogb + d0);
        f32x4 c4  = *(const f32x4*)(bogA + d0);
        f32x4 c5  = *(const f32x4*)(bctb + d0);
        f32x4 vfw = *(const f32x4*)(fw + d0);
        #pragma unroll
        for (int j = 0; j < 4; ++j) {
            const float fg = sigm(vfg[j] + c1[j]);
            const float ig = sigm(vig[j] + c2[j]);
            const float og = sigm(vog[j] + c3[j] + c4[j]);
            const float ct = fg * va[j] + ig * tanhf(vct[j] + c5[j]);
            const float ht = og * sigm(ct);
            hsum += ht * vfw[j];
            av[c * 4 + j]  = va[j];
            bvv[c * 4 + j] = vb[j];
        }
    }
    #pragma unroll
    for (int off = 32; off; off >>= 1) hsum += __shfl_xor(hsum, off);
    const float score = sigm(hsum + fb[0]);
    #pragma unroll
    for (int c = 0; c < 2; ++c) {
        const int d0 = c * 256 + lane * 4;
        f32x4 o;
        #pragma unroll
        for (int j = 0; j < 4; ++j) {
            const float a = av[c * 4 + j];
            o[j] = a - (a - bvv[c * 4 + j]) * score;
        }
        *(f32x4*)(out + (size_t)b * ND + d0) = o;
    }
    if (lane == 0) out[(size_t)NB * ND + b] = score;
}

extern "C" void kernel_launch(void* const* d_in, const int* in_sizes, int n_in,
                              void* d_out, int out_size, void* d_ws, size_t ws_size,
                              hipStream_t stream) {
    const int*   ip    = (const int*)d_in[0];
    const float* src   = (const float*)d_in[1];
    const float* enc   = (const float*)d_in[2];
    const float* prev  = (const float*)d_in[3];
    const float* sv    = (const float*)d_in[4];
    const float* Wfg_w = (const float*)d_in[5];
    const float* Wfg_b = (const float*)d_in[6];
    const float* Wig_w = (const float*)d_in[7];
    const float* Wig_b = (const float*)d_in[8];
    const float* Wogb_w = (const float*)d_in[9];
    const float* Wogb_b = (const float*)d_in[10];
    const float* WogA_w = (const float*)d_in[11];
    const float* WogA_b = (const float*)d_in[12];
    const float* Wctb_w = (const float*)d_in[13];
    const float* Wctb_b = (const float*)d_in[14];
    const float* fw    = (const float*)d_in[15];
    const float* fb    = (const float*)d_in[16];

    char* ws = (char*)d_ws;
    short* X1 = (short*)(ws + 0);          // 4096*1088*2 = 8,912,896
    short* X2 = (short*)(ws + 8912896);    // 4096*1024*2 = 8,388,608
    short* W1 = (short*)(ws + 17301504);   // 1024*1088*2 = 2,228,224
    short* W2 = (short*)(ws + 19529728);   // 1024*1024*2 = 2,097,152
    float* G1 = (float*)(ws + 21626880);   // 4096*1024*4 = 16,777,216
    float* G2 = (float*)(ws + 38404096);   // 16,777,216 ; total 55,181,312 B

    prep1<<<1024, 256, 0, stream>>>(ip, src, prev, sv, X1, X2);
    prep2<<<4096, 256, 0, stream>>>(ip, enc, X1);
    build_w<<<8448, 256, 0, stream>>>(Wfg_w, Wig_w, Wogb_w, WogA_w, Wctb_w, W1, W2);
    gemm_bt<<<dim3(32, 8, 2), 256, 0, stream>>>(X1, W1, G1, X2, W2, G2);
    finish_k<<<1024, 256, 0, stream>>>(ip, src, prev, G1, G2, Wfg_b, Wig_b, Wogb_b, WogA_b,
                                       Wctb_b, fw, fb, (float*)d_out);
}

// Round 3
// 63.362 us; speedup vs baseline: 1.0285x; 1.0285x over previous
//
#include <hip/hip_runtime.h>
#include <hip/hip_bf16.h>
#include <stdint.h>

#define NB 4096
#define NS 64
#define ND 512
#define K1 1088   // 1026 padded to multiple of 64
#define EPSV 1e-8f

typedef float f32x4 __attribute__((ext_vector_type(4)));
typedef short bf16x8 __attribute__((ext_vector_type(8)));

__device__ __forceinline__ short f2bf(float f) {
    union { float f; unsigned u; } v; v.f = f;
    unsigned r = v.u + 0x7fffu + ((v.u >> 16) & 1u);
    return (short)(r >> 16);
}
__device__ __forceinline__ float bf2f(short s) {
    union { unsigned u; float f; } v; v.u = ((unsigned)(unsigned short)s) << 16;
    return v.f;
}
__device__ __forceinline__ float sigm(float x) { return 1.0f / (1.0f + expf(-x)); }

// ---------------- prep1: cosine sims + X2=[Bv|A] bf16 + X1 tail ----------------
__global__ __launch_bounds__(256) void prep1(
    const int* __restrict__ ip, const float* __restrict__ src,
    const float* __restrict__ Aa, const float* __restrict__ sv,
    short* __restrict__ X1, short* __restrict__ X2)
{
    const int i = *ip;
    const int w = threadIdx.x >> 6, lane = threadIdx.x & 63;
    const int b = blockIdx.x * 4 + w;
    const float* Arow = Aa + (size_t)b * ND;
    const float* Brow = src + ((size_t)b * NS + i) * ND;
    const float* Srow = sv + (size_t)b * ND;
    short* x2row = X2 + (size_t)b * 1024;

    float dab = 0.f, daa = 0.f, dbb = 0.f, das = 0.f, dss = 0.f;
    #pragma unroll
    for (int c = 0; c < 2; ++c) {
        const int d0 = c * 256 + lane * 4;
        f32x4 a  = *(const f32x4*)(Arow + d0);
        f32x4 bv = *(const f32x4*)(Brow + d0);
        f32x4 s  = *(const f32x4*)(Srow + d0);
        #pragma unroll
        for (int j = 0; j < 4; ++j) {
            dab += a[j] * bv[j];
            daa += a[j] * a[j];
            dbb += bv[j] * bv[j];
            das += a[j] * s[j];
            dss += s[j] * s[j];
        }
        short4 qb, qa;
        qb.x = f2bf(bv[0]); qb.y = f2bf(bv[1]); qb.z = f2bf(bv[2]); qb.w = f2bf(bv[3]);
        qa.x = f2bf(a[0]);  qa.y = f2bf(a[1]);  qa.z = f2bf(a[2]);  qa.w = f2bf(a[3]);
        *(short4*)(x2row + d0) = qb;
        *(short4*)(x2row + 512 + d0) = qa;
    }
    #pragma unroll
    for (int off = 32; off; off >>= 1) {
        dab += __shfl_xor(dab, off);
        daa += __shfl_xor(daa, off);
        dbb += __shfl_xor(dbb, off);
        das += __shfl_xor(das, off);
        dss += __shfl_xor(dss, off);
    }
    const float na = fmaxf(sqrtf(daa), EPSV);
    const float nb = fmaxf(sqrtf(dbb), EPSV);
    const float ns = fmaxf(sqrtf(dss), EPSV);
    short* x1row = X1 + (size_t)b * K1;
    if (lane == 0) {
        x1row[1024] = f2bf(dab / (na * nb));
        x1row[1025] = f2bf(das / (na * ns));
    }
    if (lane < 62) x1row[1026 + lane] = 0;   // zero pad cols 1026..1087
}

// ---------------- prep2: enc_memory[i] -> X1 bf16 (cols 0..1023) ----------------
__global__ __launch_bounds__(256) void prep2(
    const int* __restrict__ ip, const float* __restrict__ enc, short* __restrict__ X1)
{
    const int i = *ip;
    const int idx = blockIdx.x * 256 + threadIdx.x;
    const int b = idx >> 8;
    const int k4 = (idx & 255) * 4;
    f32x4 v = *(const f32x4*)(enc + ((size_t)i * NB + b) * 1024 + k4);
    short4 q;
    q.x = f2bf(v[0]); q.y = f2bf(v[1]); q.z = f2bf(v[2]); q.w = f2bf(v[3]);
    *(short4*)(X1 + (size_t)b * K1 + k4) = q;
}

// ---------------- pack_w: bf16 weight blocks W1 / Wog / Wct ----------------
// flat 1,900,544 elems: [0,1114112) W1 ; [1114112,1638400) Wog ; rest Wct
__global__ __launch_bounds__(256) void pack_w(
    const float* __restrict__ Wfg, const float* __restrict__ Wig,
    const float* __restrict__ Wogb, const float* __restrict__ WogA,
    const float* __restrict__ Wctb,
    short* __restrict__ W1, short* __restrict__ Wog, short* __restrict__ Wct)
{
    const int idx = blockIdx.x * 256 + threadIdx.x;
    if (idx < 1114112) {
        const int n = idx / 1088, k = idx - n * 1088;
        float v = 0.f;
        if (k < 1026) v = (n < 512) ? Wfg[(size_t)n * 1026 + k] : Wig[(size_t)(n - 512) * 1026 + k];
        W1[idx] = f2bf(v);
    } else if (idx < 1638400) {
        const int j = idx - 1114112;
        const int n = j >> 10, k = j & 1023;
        const float v = (k < 512) ? Wogb[(size_t)n * 512 + k] : WogA[(size_t)n * 512 + (k - 512)];
        Wog[j] = f2bf(v);
    } else {
        const int j = idx - 1638400;   // [0, 262144)
        Wct[j] = f2bf(Wctb[j]);
    }
}

// ---------------- gemm: three segments in one flat grid, bf16 output ----------------
// gid [0,256):  Gfi = X1(4096xK1) @ W1(1024xK1)^T           tiles 32x8
// gid [256,384): Gog = X2(4096x1024) @ Wog(512x1024)^T      tiles 32x4
// gid [384,512): Gct = X2[:, :512] @ Wct(512x512)^T         tiles 32x4
__global__ __launch_bounds__(256) void gemm_bt(
    const short* __restrict__ X1v, const short* __restrict__ W1v,
    const short* __restrict__ X2v, const short* __restrict__ Wogv,
    const short* __restrict__ Wctv,
    short* __restrict__ Gfi, short* __restrict__ Gog, short* __restrict__ Gct)
{
    __shared__ __align__(16) short As[128 * 64];
    __shared__ __align__(16) short Bs[128 * 64];

    const int gid = blockIdx.x;
    const short *Xp, *Wp;
    short* Gp;
    int bx, by, xs, wss, gs, nkt;
    if (gid < 256)      { bx = gid >> 3;          by = gid & 7;          Xp = X1v; Wp = W1v;  Gp = Gfi; xs = K1;   wss = K1;   gs = 1024; nkt = 17; }
    else if (gid < 384) { bx = (gid - 256) >> 2;  by = (gid - 256) & 3;  Xp = X2v; Wp = Wogv; Gp = Gog; xs = 1024; wss = 1024; gs = 512;  nkt = 16; }
    else                { bx = (gid - 384) >> 2;  by = (gid - 384) & 3;  Xp = X2v; Wp = Wctv; Gp = Gct; xs = 1024; wss = 512;  gs = 512;  nkt = 8;  }

    const int tid = threadIdx.x;
    const int w = tid >> 6, lane = tid & 63;
    const int wm = w >> 1, wn = w & 1;
    const int lr = lane & 15, lg = lane >> 4;

    const size_t ldx = (size_t)xs * 2;   // X row stride bytes
    const size_t ldw = (size_t)wss * 2;  // W row stride bytes
    const char* Xb = (const char*)Xp + (size_t)bx * 128 * ldx;
    const char* Wb = (const char*)Wp + (size_t)by * 128 * ldw;

    f32x4 acc[4][4];
    #pragma unroll
    for (int mi = 0; mi < 4; ++mi)
        #pragma unroll
        for (int ni = 0; ni < 4; ++ni)
            acc[mi][ni] = f32x4{0.f, 0.f, 0.f, 0.f};

    for (int kt = 0; kt < nkt; ++kt) {
        __syncthreads();
        #pragma unroll
        for (int s = 0; s < 4; ++s) {
            const int seg = (s * 4 + w) * 1024;
            const int linear = seg + lane * 16;
            const int row = linear >> 7, kb = linear & 127;
            __builtin_amdgcn_global_load_lds(
                (const __attribute__((address_space(1))) void*)(Xb + (size_t)row * ldx + (size_t)kt * 128 + kb),
                (__attribute__((address_space(3))) void*)((char*)As + seg),
                16, 0, 0);
        }
        #pragma unroll
        for (int s = 0; s < 4; ++s) {
            const int seg = (s * 4 + w) * 1024;
            const int linear = seg + lane * 16;
            const int row = linear >> 7, kb = linear & 127;
            __builtin_amdgcn_global_load_lds(
                (const __attribute__((address_space(1))) void*)(Wb + (size_t)row * ldw + (size_t)kt * 128 + kb),
                (__attribute__((address_space(3))) void*)((char*)Bs + seg),
                16, 0, 0);
        }
        __syncthreads();
        #pragma unroll
        for (int ks = 0; ks < 2; ++ks) {
            bf16x8 af[4], bfr[4];
            #pragma unroll
            for (int mi = 0; mi < 4; ++mi)
                af[mi] = *(const bf16x8*)((const char*)As + (wm * 64 + mi * 16 + lr) * 128 + ks * 64 + lg * 16);
            #pragma unroll
            for (int ni = 0; ni < 4; ++ni)
                bfr[ni] = *(const bf16x8*)((const char*)Bs + (wn * 64 + ni * 16 + lr) * 128 + ks * 64 + lg * 16);
            #pragma unroll
            for (int mi = 0; mi < 4; ++mi)
                #pragma unroll
                for (int ni = 0; ni < 4; ++ni)
                    acc[mi][ni] = __builtin_amdgcn_mfma_f32_16x16x32_bf16(af[mi], bfr[ni], acc[mi][ni], 0, 0, 0);
        }
    }

    short* Grow = Gp + ((size_t)bx * 128 + wm * 64) * gs + by * 128 + wn * 64;
    #pragma unroll
    for (int mi = 0; mi < 4; ++mi)
        #pragma unroll
        for (int ni = 0; ni < 4; ++ni)
            #pragma unroll
            for (int r = 0; r < 4; ++r)
                Grow[(size_t)(mi * 16 + lg * 4 + r) * gs + ni * 16 + lr] = f2bf(acc[mi][ni][r]);
}

// ---------------- finish: gates + score + out ----------------
__global__ __launch_bounds__(256) void finish_k(
    const int* __restrict__ ip, const float* __restrict__ src, const float* __restrict__ Aa,
    const short* __restrict__ Gfi, const short* __restrict__ Gog, const short* __restrict__ Gct,
    const float* __restrict__ bfg, const float* __restrict__ big,
    const float* __restrict__ bogb, const float* __restrict__ bogA, const float* __restrict__ bctb,
    const float* __restrict__ fw, const float* __restrict__ fb,
    float* __restrict__ out)
{
    const int i = *ip;
    const int w = threadIdx.x >> 6, lane = threadIdx.x & 63;
    const int b = blockIdx.x * 4 + w;
    const int d = lane * 8;
    const float* Arow = Aa + (size_t)b * ND;
    const float* Brow = src + ((size_t)b * NS + i) * ND;

    bf16x8 vfg = *(const bf16x8*)(Gfi + (size_t)b * 1024 + d);
    bf16x8 vig = *(const bf16x8*)(Gfi + (size_t)b * 1024 + 512 + d);
    bf16x8 vog = *(const bf16x8*)(Gog + (size_t)b * 512 + d);
    bf16x8 vct = *(const bf16x8*)(Gct + (size_t)b * 512 + d);

    float hsum = 0.f;
    float av[8], bvv[8];
    #pragma unroll
    for (int c = 0; c < 2; ++c) {
        const int d0 = d + c * 4;
        f32x4 va = *(const f32x4*)(Arow + d0);
        f32x4 vb = *(const f32x4*)(Brow + d0);
        f32x4 c1 = *(const f32x4*)(bfg + d0);
        f32x4 c2 = *(const f32x4*)(big + d0);
        f32x4 c3 = *(const f32x4*)(bogb + d0);
        f32x4 c4 = *(const f32x4*)(bogA + d0);
        f32x4 c5 = *(const f32x4*)(bctb + d0);
        f32x4 vfw = *(const f32x4*)(fw + d0);
        #pragma unroll
        for (int j = 0; j < 4; ++j) {
            const int e = c * 4 + j;
            const float fg = sigm(bf2f(vfg[e]) + c1[j]);
            const float ig = sigm(bf2f(vig[e]) + c2[j]);
            const float og = sigm(bf2f(vog[e]) + c3[j] + c4[j]);
            const float ct = fg * va[j] + ig * tanhf(bf2f(vct[e]) + c5[j]);
            const float ht = og * sigm(ct);
            hsum += ht * vfw[j];
            av[e] = va[j]; bvv[e] = vb[j];
        }
    }
    #pragma unroll
    for (int off = 32; off; off >>= 1) hsum += __shfl_xor(hsum, off);
    const float score = sigm(hsum + fb[0]);
    #pragma unroll
    for (int c = 0; c < 2; ++c) {
        f32x4 o;
        #pragma unroll
        for (int j = 0; j < 4; ++j) {
            const float a = av[c * 4 + j];
            o[j] = a - (a - bvv[c * 4 + j]) * score;
        }
        *(f32x4*)(out + (size_t)b * ND + d + c * 4) = o;
    }
    if (lane == 0) out[(size_t)NB * ND + b] = score;
}

extern "C" void kernel_launch(void* const* d_in, const int* in_sizes, int n_in,
                              void* d_out, int out_size, void* d_ws, size_t ws_size,
                              hipStream_t stream) {
    const int*   ip    = (const int*)d_in[0];
    const float* src   = (const float*)d_in[1];
    const float* enc   = (const float*)d_in[2];
    const float* prev  = (const float*)d_in[3];
    const float* sv    = (const float*)d_in[4];
    const float* Wfg_w = (const float*)d_in[5];
    const float* Wfg_b = (const float*)d_in[6];
    const float* Wig_w = (const float*)d_in[7];
    const float* Wig_b = (const float*)d_in[8];
    const float* Wogb_w = (const float*)d_in[9];
    const float* Wogb_b = (const float*)d_in[10];
    const float* WogA_w = (const float*)d_in[11];
    const float* WogA_b = (const float*)d_in[12];
    const float* Wctb_w = (const float*)d_in[13];
    const float* Wctb_b = (const float*)d_in[14];
    const float* fw    = (const float*)d_in[15];
    const float* fb    = (const float*)d_in[16];

    char* ws = (char*)d_ws;
    short* X1  = (short*)(ws + 0);          // 4096*1088*2 = 8,912,896
    short* X2  = (short*)(ws + 8912896);    // 4096*1024*2 = 8,388,608
    short* W1  = (short*)(ws + 17301504);   // 1024*1088*2 = 2,228,224
    short* Wog = (short*)(ws + 19529728);   // 512*1024*2  = 1,048,576
    short* Wct = (short*)(ws + 20578304);   // 512*512*2   =   524,288
    short* Gfi = (short*)(ws + 21102592);   // 4096*1024*2 = 8,388,608
    short* Gog = (short*)(ws + 29491200);   // 4096*512*2  = 4,194,304
    short* Gct = (short*)(ws + 33685504);   // 4,194,304 ; end 37,879,808

    prep1<<<1024, 256, 0, stream>>>(ip, src, prev, sv, X1, X2);
    prep2<<<4096, 256, 0, stream>>>(ip, enc, X1);
    pack_w<<<7424, 256, 0, stream>>>(Wfg_w, Wig_w, Wogb_w, WogA_w, Wctb_w, W1, Wog, Wct);
    gemm_bt<<<512, 256, 0, stream>>>(X1, W1, X2, Wog, Wct, Gfi, Gog, Gct);
    finish_k<<<1024, 256, 0, stream>>>(ip, src, prev, Gfi, Gog, Gct,
                                       Wfg_b, Wig_b, Wogb_b, WogA_b, Wctb_b,
                                       fw, fb, (float*)d_out);
}